// Round 1
// baseline (81.522 us; speedup 1.0000x reference)
//
#include <hip/hip_runtime.h>
#include <math.h>

// out[n] = max_c min_{k!=c} [2(mu_c-mu_k).x + ||mu_k||^2 - ||mu_c||^2]
//        = top1(s) - top2(s),  s_c = 2 mu_c.x - ||mu_c||^2
//
// Block = 256 threads = 4 waves; wave w owns centroids k in [8w, 8w+8),
// held fully in VGPRs (lane i owns dims {256j + 4i .. +3}, j=0..3).
// X streamed from global, coalesced, read once; 4 waves share rows via L1
// (kept in lockstep with a raw s_barrier every 8 rows).
// Per-row dot partials reduced with a value-splitting butterfly (bit-reversed
// k mapping); s values gathered in LDS; top-2 per row at batch end.

#define BLOCK 256
#define RPB   64
#define KTOT  32
#define DDIM  1024

__device__ __forceinline__ float reduce8_bitrev(float (&v)[8], int lane) {
  // Sums each of 8 per-lane partials across all 64 lanes.
  // Lane ends holding k_local = ((lane&1)<<2) | (lane&2) | ((lane>>2)&1).
  const bool b0 = (lane & 1) != 0;
  float t0, t1, t2, t3;
  {
    float s, k_;
    s = b0 ? v[0] : v[4];  k_ = b0 ? v[4] : v[0];  t0 = k_ + __shfl_xor(s, 1, 64);
    s = b0 ? v[1] : v[5];  k_ = b0 ? v[5] : v[1];  t1 = k_ + __shfl_xor(s, 1, 64);
    s = b0 ? v[2] : v[6];  k_ = b0 ? v[6] : v[2];  t2 = k_ + __shfl_xor(s, 1, 64);
    s = b0 ? v[3] : v[7];  k_ = b0 ? v[7] : v[3];  t3 = k_ + __shfl_xor(s, 1, 64);
  }
  const bool b1 = (lane & 2) != 0;
  float u0, u1;
  {
    float s, k_;
    s = b1 ? t0 : t2;  k_ = b1 ? t2 : t0;  u0 = k_ + __shfl_xor(s, 2, 64);
    s = b1 ? t1 : t3;  k_ = b1 ? t3 : t1;  u1 = k_ + __shfl_xor(s, 2, 64);
  }
  const bool b2 = (lane & 4) != 0;
  float r;
  {
    float s  = b2 ? u0 : u1;
    float k_ = b2 ? u1 : u0;
    r = k_ + __shfl_xor(s, 4, 64);
  }
  r += __shfl_xor(r, 8, 64);
  r += __shfl_xor(r, 16, 64);
  r += __shfl_xor(r, 32, 64);
  return r;
}

__global__ __launch_bounds__(BLOCK, 2)
void nkm_top2_kernel(const float* __restrict__ X,
                     const float* __restrict__ Cent,
                     float* __restrict__ out, int N) {
  const int tid  = threadIdx.x;
  const int lane = tid & 63;
  const int wid  = tid >> 6;   // wave id 0..3
  const int kb   = wid * 8;    // this wave's centroid base
  const int rowbase = blockIdx.x * RPB;
  const int kmap = ((lane & 1) << 2) | (lane & 2) | ((lane >> 2) & 1);

  __shared__ float s_lds[RPB][KTOT + 1];

  // ---- centroids -> registers: c[k][j] = Cent[kb+k][256j + 4*lane .. +3]
  float4 c[8][4];
  #pragma unroll
  for (int k = 0; k < 8; ++k) {
    const float* cp = Cent + (size_t)(kb + k) * DDIM + (lane << 2);
    #pragma unroll
    for (int j = 0; j < 4; ++j)
      c[k][j] = *(const float4*)(cp + j * 256);
  }

  // ---- ||mu_k||^2 partials, reduced with the SAME lane->k mapping as s
  float sq[8];
  #pragma unroll
  for (int k = 0; k < 8; ++k) {
    float s = 0.f;
    #pragma unroll
    for (int j = 0; j < 4; ++j) {
      float4 a = c[k][j];
      s = fmaf(a.x, a.x, s); s = fmaf(a.y, a.y, s);
      s = fmaf(a.z, a.z, s); s = fmaf(a.w, a.w, s);
    }
    sq[k] = s;
  }
  const float sqv = reduce8_bitrev(sq, lane);

  float4 xA[4], xB[4], xC[4];

#define LOADROW(r, B) do {                                              \
    int g_ = rowbase + (r); if (g_ > N - 1) g_ = N - 1;                 \
    const float* p_ = X + (size_t)g_ * DDIM + (lane << 2);              \
    B[0] = *(const float4*)(p_);                                        \
    B[1] = *(const float4*)(p_ + 256);                                  \
    B[2] = *(const float4*)(p_ + 512);                                  \
    B[3] = *(const float4*)(p_ + 768);                                  \
  } while (0)

#define COMPROW(r, B) do {                                              \
    float acc[8];                                                       \
    _Pragma("unroll") for (int k = 0; k < 8; ++k) acc[k] = 0.f;         \
    _Pragma("unroll") for (int k = 0; k < 8; ++k) {                     \
      _Pragma("unroll") for (int j = 0; j < 4; ++j) {                   \
        acc[k] = fmaf(B[j].x, c[k][j].x, acc[k]);                       \
        acc[k] = fmaf(B[j].y, c[k][j].y, acc[k]);                       \
        acc[k] = fmaf(B[j].z, c[k][j].z, acc[k]);                       \
        acc[k] = fmaf(B[j].w, c[k][j].w, acc[k]);                       \
      }                                                                 \
    }                                                                   \
    float red_ = reduce8_bitrev(acc, lane);                             \
    if (lane < 8) s_lds[(r)][kb + kmap] = fmaf(2.f, red_, -sqv);        \
    if (((r) & 7) == 7) __builtin_amdgcn_s_barrier();                   \
  } while (0)

  // 3-buffer software pipeline, prefetch distance 2 rows
  LOADROW(0, xA);
  LOADROW(1, xB);
  #pragma unroll 1
  for (int rt = 0; rt < 63; rt += 3) {
    LOADROW(rt + 2, xC); COMPROW(rt + 0, xA);
    LOADROW(rt + 3, xA); COMPROW(rt + 1, xB);
    LOADROW(rt + 4, xB); COMPROW(rt + 2, xC);
  }
  COMPROW(63, xA);

#undef LOADROW
#undef COMPROW

  __syncthreads();

  // ---- per-row top-2 over the 32 scores
  if (tid < RPB) {
    int g = rowbase + tid;
    if (g < N) {
      float m1 = -INFINITY, m2 = -INFINITY;
      #pragma unroll
      for (int k = 0; k < KTOT; ++k) {
        float v = s_lds[tid][k];
        m2 = fmaxf(m2, fminf(m1, v));
        m1 = fmaxf(m1, v);
      }
      out[g] = m1 - m2;
    }
  }
}

extern "C" void kernel_launch(void* const* d_in, const int* in_sizes, int n_in,
                              void* d_out, int out_size, void* d_ws, size_t ws_size,
                              hipStream_t stream) {
  const float* X = (const float*)d_in[0];
  const float* C = (const float*)d_in[1];
  float* out = (float*)d_out;
  const int N = in_sizes[0] / DDIM;  // 50000
  const int blocks = (N + RPB - 1) / RPB;  // 782
  hipLaunchKernelGGL(nkm_top2_kernel, dim3(blocks), dim3(BLOCK), 0, stream,
                     X, C, out, N);
}

// Round 2
// 65.778 us; speedup vs baseline: 1.2393x; 1.2393x over previous
//
#include <hip/hip_runtime.h>
#include <math.h>

// out[n] = top1(s) - top2(s),  s_c = 2 mu_c.x - ||mu_c||^2
// GEMM via mfma_f32_16x16x32_bf16: A = X rows (bf16, cvt on the fly),
// B = centroids (bf16 fragment table in 64KB LDS), fp32 accum.
// ||mu||^2 kept fp32 (computed via LDS scratch before frag table overwrites it).
//
// Block = 256 threads = 4 waves; wave w owns rows [blk*64 + 16w, +16).
// Per wave: acc0 = cols 0-15, acc1 = cols 16-31 (two MFMA chains, K=1024).
// A and B use the SAME assumed k-slot mapping -> correct under any true
// per-slot k permutation (summation-index permutation invariance).

#define KTOT  32
#define DDIM  1024
#define BLOCK 256
#define RPB   64

typedef __attribute__((ext_vector_type(8))) short short8v;
typedef __attribute__((ext_vector_type(4))) float f32x4;

__device__ __forceinline__ short f2bf(float x) {  // RNE fp32 -> bf16
  unsigned u = __float_as_uint(x);
  u += 0x7fffu + ((u >> 16) & 1u);
  return (short)(u >> 16);
}

__global__ __launch_bounds__(BLOCK, 2)
void nkm_mfma_kernel(const float* __restrict__ X,
                     const float* __restrict__ Cent,
                     float* __restrict__ out, int N) {
  __shared__ short ldsB[32768];   // exactly 64 KB: [s*2+t][lane][8] bf16 frags

  const int tid  = threadIdx.x;
  const int lane = tid & 63;
  const int wid  = tid >> 6;
  const int g    = lane >> 4;     // 16-lane group 0..3
  const int cc   = lane & 15;     // col within tile / A-row within tile

  // ---- phase 1: ||mu_k||^2 partials into LDS scratch (reused as ldsB later)
  {
    float* scratch = (float*)ldsB;             // 8*32 floats = 1 KB
    const int k = tid & 31, seg = tid >> 5;    // 8 segs x 128 dims
    const float* cp = Cent + (size_t)k * DDIM + seg * 128;
    float a0 = 0.f, a1 = 0.f, a2 = 0.f, a3 = 0.f;
    #pragma unroll
    for (int j = 0; j < 32; ++j) {
      float4 v = *(const float4*)(cp + j * 4);
      a0 = fmaf(v.x, v.x, a0); a1 = fmaf(v.y, v.y, a1);
      a2 = fmaf(v.z, v.z, a2); a3 = fmaf(v.w, v.w, a3);
    }
    scratch[seg * 32 + k] = (a0 + a1) + (a2 + a3);
  }
  __syncthreads();

  // ---- phase 2: every thread reduces the two sq values it needs into regs
  float sq0 = 0.f, sq1 = 0.f;
  {
    const float* scratch = (const float*)ldsB;
    #pragma unroll
    for (int seg = 0; seg < 8; ++seg) {
      sq0 += scratch[seg * 32 + cc];
      sq1 += scratch[seg * 32 + 16 + cc];
    }
  }
  __syncthreads();

  // ---- phase 3: build bf16 B-fragment table (overwrites scratch)
  // item i = (st*64 + l), st = s*2+t; frag lane l slot e <-> dim s*32+(l>>4)*8+e
  #pragma unroll
  for (int j = 0; j < 16; ++j) {
    const int i  = tid + j * 256;   // 0..4095
    const int l  = i & 63;
    const int st = i >> 6;
    const int col = ((st & 1) << 4) | (l & 15);
    const int d0  = ((st >> 1) << 5) + ((l >> 4) << 3);
    const float* cp = Cent + (size_t)col * DDIM + d0;
    float4 f0 = *(const float4*)cp;
    float4 f1 = *(const float4*)(cp + 4);
    short8v b;
    b[0] = f2bf(f0.x); b[1] = f2bf(f0.y); b[2] = f2bf(f0.z); b[3] = f2bf(f0.w);
    b[4] = f2bf(f1.x); b[5] = f2bf(f1.y); b[6] = f2bf(f1.z); b[7] = f2bf(f1.w);
    *(short8v*)&ldsB[(size_t)i * 8] = b;
  }
  __syncthreads();

  // ---- main: 16 rows per wave, K = 1024 in 32 MFMA steps, prefetch depth 4
  int row = blockIdx.x * RPB + wid * 16 + cc;
  if (row > N - 1) row = N - 1;
  const float* pA = X + (size_t)row * DDIM + (g << 3);

  float4 buf[4][2];
  #pragma unroll
  for (int p = 0; p < 4; ++p) {
    buf[p][0] = *(const float4*)(pA + p * 32);
    buf[p][1] = *(const float4*)(pA + p * 32 + 4);
  }

  f32x4 acc0 = {0.f, 0.f, 0.f, 0.f};
  f32x4 acc1 = {0.f, 0.f, 0.f, 0.f};

  #pragma unroll
  for (int s = 0; s < 32; ++s) {
    const short8v b0 = *(const short8v*)&ldsB[(size_t)(((s << 1) | 0) * 64 + lane) * 8];
    const short8v b1 = *(const short8v*)&ldsB[(size_t)(((s << 1) | 1) * 64 + lane) * 8];
    const float4 f0 = buf[s & 3][0];
    const float4 f1 = buf[s & 3][1];
    short8v a;
    a[0] = f2bf(f0.x); a[1] = f2bf(f0.y); a[2] = f2bf(f0.z); a[3] = f2bf(f0.w);
    a[4] = f2bf(f1.x); a[5] = f2bf(f1.y); a[6] = f2bf(f1.z); a[7] = f2bf(f1.w);
    if (s < 28) {   // prefetch step s+4 into the buffer just consumed
      buf[s & 3][0] = *(const float4*)(pA + (s + 4) * 32);
      buf[s & 3][1] = *(const float4*)(pA + (s + 4) * 32 + 4);
    }
    acc0 = __builtin_amdgcn_mfma_f32_16x16x32_bf16(a, b0, acc0, 0, 0, 0);
    acc1 = __builtin_amdgcn_mfma_f32_16x16x32_bf16(a, b1, acc1, 0, 0, 0);
  }

  // ---- epilogue: s = 2*dot - sq; top-2 across 16 lanes x 2 cols each
  const int rbase = blockIdx.x * RPB + wid * 16 + (g << 2);
  #pragma unroll
  for (int r = 0; r < 4; ++r) {
    float v0 = fmaf(2.f, acc0[r], -sq0);
    float v1 = fmaf(2.f, acc1[r], -sq1);
    float m1 = fmaxf(v0, v1);
    float m2 = fminf(v0, v1);
    #pragma unroll
    for (int d = 1; d <= 8; d <<= 1) {
      float om1 = __shfl_xor(m1, d, 64);
      float om2 = __shfl_xor(m2, d, 64);
      m2 = fmaxf(fmaxf(fminf(m1, om1), om2), m2);  // merged top-2
      m1 = fmaxf(m1, om1);
    }
    const int orow = rbase + r;
    if (cc == 0 && orow < N) out[orow] = m1 - m2;
  }
}

extern "C" void kernel_launch(void* const* d_in, const int* in_sizes, int n_in,
                              void* d_out, int out_size, void* d_ws, size_t ws_size,
                              hipStream_t stream) {
  const float* X = (const float*)d_in[0];
  const float* C = (const float*)d_in[1];
  float* out = (float*)d_out;
  const int N = in_sizes[0] / DDIM;            // 50000
  const int blocks = (N + RPB - 1) / RPB;      // 782
  hipLaunchKernelGGL(nkm_mfma_kernel, dim3(blocks), dim3(BLOCK), 0, stream,
                     X, C, out, N);
}

// Round 3
// 45.073 us; speedup vs baseline: 1.8087x; 1.4594x over previous
//
#include <hip/hip_runtime.h>
#include <math.h>

// out[n] = top1(s) - top2(s),  s_c = 2 mu_c.x - ||mu_c||^2
//
// Kernel 1 (96 blocks x 64 thr): precompute into d_ws
//   - 64 KB bf16 B-fragment table for mfma_f32_16x16x32_bf16 (swizzled)
//   - 32 fp32 ||mu_c||^2
// Kernel 2 (511 blocks x 512 thr, 98 rows/block): stage table into LDS once,
//   stream X coalesced (read exactly once), 2 MFMA chains per wave (cols 0-15
//   and 16-31), register top-2 epilogue via merged shfl_xor reduction.
//   2 blocks/CU resident (128 KB LDS) -> 4 waves/SIMD.
// A and B use the same k-slot mapping -> dot invariant to slot permutation.

#define KTOT  32
#define DDIM  1024
#define BLK2  512
#define RPB2  98     // rows per block (6.125 waves of 16)

typedef __attribute__((ext_vector_type(8))) short short8v;
typedef __attribute__((ext_vector_type(4))) float f32x4;

__device__ __forceinline__ short f2bf(float x) {  // RNE fp32 -> bf16
  unsigned u = __float_as_uint(x);
  u += 0x7fffu + ((u >> 16) & 1u);
  return (short)(u >> 16);
}

// ---------------- kernel 1: build fragment table + sq in workspace ---------
__global__ __launch_bounds__(64)
void nkm_pre_kernel(const float* __restrict__ Cent, short* __restrict__ tbl) {
  const int b = blockIdx.x, t = threadIdx.x;
  if (b < 64) {
    // fragment item i: st = i>>6 (k-step*2 + col-half), l = i&63 (frag lane)
    const int i  = b * 64 + t;          // 0..4095
    const int l  = i & 63;
    const int st = i >> 6;
    const int col = ((st & 1) << 4) | (l & 15);
    const int d0  = ((st >> 1) << 5) + ((l >> 4) << 3);
    const float* cp = Cent + (size_t)col * DDIM + d0;
    float4 f0 = *(const float4*)cp;
    float4 f1 = *(const float4*)(cp + 4);
    short8v v;
    v[0] = f2bf(f0.x); v[1] = f2bf(f0.y); v[2] = f2bf(f0.z); v[3] = f2bf(f0.w);
    v[4] = f2bf(f1.x); v[5] = f2bf(f1.y); v[6] = f2bf(f1.z); v[7] = f2bf(f1.w);
    *(short8v*)(tbl + (size_t)i * 8) = v;
  } else {
    // ||mu_col||^2, one wave per col
    const int col = b - 64;             // 0..31
    const float* cp = Cent + (size_t)col * DDIM + t * 16;
    float a0 = 0.f, a1 = 0.f, a2 = 0.f, a3 = 0.f;
    #pragma unroll
    for (int j = 0; j < 4; ++j) {
      float4 v = *(const float4*)(cp + j * 4);
      a0 = fmaf(v.x, v.x, a0); a1 = fmaf(v.y, v.y, a1);
      a2 = fmaf(v.z, v.z, a2); a3 = fmaf(v.w, v.w, a3);
    }
    float s = (a0 + a1) + (a2 + a3);
    #pragma unroll
    for (int d = 1; d < 64; d <<= 1) s += __shfl_xor(s, d, 64);
    if (t == 0) ((float*)(tbl + 32768))[col] = s;
  }
}

// ---------------- kernel 2: stream X, MFMA, top-2 --------------------------
__global__ __launch_bounds__(BLK2, 4)
void nkm_main_kernel(const float* __restrict__ X,
                     const short* __restrict__ tbl,
                     float* __restrict__ out, int N) {
  __shared__ short ldsB[32768];   // 64 KB fragment table

  const int tid  = threadIdx.x;
  const int lane = tid & 63;
  const int wid  = tid >> 6;      // wave 0..7
  const int g    = lane >> 4;     // 16-lane group 0..3
  const int cc   = lane & 15;

  // stage table: 8 rounds x 512 thr x 16 B (coalesced, conflict-free)
  #pragma unroll
  for (int r = 0; r < 8; ++r) {
    const int i = r * 512 + tid;
    *(short8v*)&ldsB[(size_t)i * 8] = *(const short8v*)(tbl + (size_t)i * 8);
  }
  const float sq0 = ((const float*)(tbl + 32768))[cc];
  const float sq1 = ((const float*)(tbl + 32768))[cc + 16];
  __syncthreads();

  const int blk_base = blockIdx.x * RPB2;
  int limit = blk_base + RPB2; if (limit > N) limit = N;
  const int rb = blk_base + wid * 16;
  if (rb >= limit) return;        // idle waves (past block's rows)

  int row = rb + cc;
  if (row >= limit) row = limit - 1;   // clamped dup load (L1 hit), store off
  const float* pA = X + (size_t)row * DDIM + (g << 3);

  float4 buf[4][2];
  #pragma unroll
  for (int p = 0; p < 4; ++p) {
    buf[p][0] = *(const float4*)(pA + p * 32);
    buf[p][1] = *(const float4*)(pA + p * 32 + 4);
  }

  f32x4 acc0 = {0.f, 0.f, 0.f, 0.f};
  f32x4 acc1 = {0.f, 0.f, 0.f, 0.f};

  #pragma unroll
  for (int s = 0; s < 32; ++s) {
    const short8v b0 = *(const short8v*)&ldsB[(size_t)(((s << 1) | 0) * 64 + lane) * 8];
    const short8v b1 = *(const short8v*)&ldsB[(size_t)(((s << 1) | 1) * 64 + lane) * 8];
    const float4 f0 = buf[s & 3][0];
    const float4 f1 = buf[s & 3][1];
    short8v a;
    a[0] = f2bf(f0.x); a[1] = f2bf(f0.y); a[2] = f2bf(f0.z); a[3] = f2bf(f0.w);
    a[4] = f2bf(f1.x); a[5] = f2bf(f1.y); a[6] = f2bf(f1.z); a[7] = f2bf(f1.w);
    if (s < 28) {   // prefetch step s+4 into the buffer just consumed
      buf[s & 3][0] = *(const float4*)(pA + (s + 4) * 32);
      buf[s & 3][1] = *(const float4*)(pA + (s + 4) * 32 + 4);
    }
    acc0 = __builtin_amdgcn_mfma_f32_16x16x32_bf16(a, b0, acc0, 0, 0, 0);
    acc1 = __builtin_amdgcn_mfma_f32_16x16x32_bf16(a, b1, acc1, 0, 0, 0);
  }

  // epilogue: s = 2*dot - sq; top-2 across 16 lanes x 2 cols each
  const int rbase = rb + (g << 2);
  #pragma unroll
  for (int r = 0; r < 4; ++r) {
    float v0 = fmaf(2.f, acc0[r], -sq0);
    float v1 = fmaf(2.f, acc1[r], -sq1);
    float m1 = fmaxf(v0, v1);
    float m2 = fminf(v0, v1);
    #pragma unroll
    for (int d = 1; d <= 8; d <<= 1) {
      float om1 = __shfl_xor(m1, d, 64);
      float om2 = __shfl_xor(m2, d, 64);
      m2 = fmaxf(fmaxf(fminf(m1, om1), om2), m2);  // merged top-2
      m1 = fmaxf(m1, om1);
    }
    const int orow = rbase + r;
    if (cc == 0 && orow < limit) out[orow] = m1 - m2;
  }
}

extern "C" void kernel_launch(void* const* d_in, const int* in_sizes, int n_in,
                              void* d_out, int out_size, void* d_ws, size_t ws_size,
                              hipStream_t stream) {
  const float* X = (const float*)d_in[0];
  const float* C = (const float*)d_in[1];
  float* out = (float*)d_out;
  short* tbl = (short*)d_ws;                   // 64 KB frags + 128 B sq
  const int N = in_sizes[0] / DDIM;            // 50000
  const int blocks = (N + RPB2 - 1) / RPB2;    // 511
  hipLaunchKernelGGL(nkm_pre_kernel, dim3(96), dim3(64), 0, stream, C, tbl);
  hipLaunchKernelGGL(nkm_main_kernel, dim3(blocks), dim3(BLK2), 0, stream,
                     X, tbl, out, N);
}